// Round 4
// baseline (2475.601 us; speedup 1.0000x reference)
//
#include <hip/hip_runtime.h>
#include <hip/hip_bf16.h>
#include <hip/hip_cooperative_groups.h>
#include <cstddef>

namespace cg = cooperative_groups;

// Problem constants
#define BB   8
#define CIN  16
#define COUT 16
#define TT   32
#define HH   16
#define WW   16
#define DIN  4096
#define DOUT 4096
#define NH   4
#define DH   1024
#define SPAT 8192            // T*H*W
#define NSEQ 256             // B*T

typedef __attribute__((ext_vector_type(8))) short  bf16x8;
typedef __attribute__((ext_vector_type(4))) float  f32x4;
typedef __attribute__((ext_vector_type(4))) unsigned short us4;
typedef unsigned short ushort_t;

static __device__ __forceinline__ ushort_t f2bf(float f) {
    union { float f; unsigned u; } v; v.f = f;
    unsigned r = (v.u + 0x7fffu + ((v.u >> 16) & 1u)) >> 16;
    return (ushort_t)r;
}
static __device__ __forceinline__ float bf2f(ushort_t u) {
    union { unsigned u; float f; } v; v.u = ((unsigned)u) << 16;
    return v.f;
}

// ---------------------------------------------------------------------------
// pack x (B,16,32,16,16) fp32 -> xt[n=b*32+t][k=c*256+hw] bf16
// ---------------------------------------------------------------------------
__global__ void pack_xt_kernel(const float* __restrict__ x, ushort_t* __restrict__ xt) {
    int idx = blockIdx.x * 256 + threadIdx.x;          // 0 .. 262143 (4 elems each)
    int n = idx >> 10, k4 = (idx & 1023) * 4;
    int b = n >> 5, t = n & 31, c = k4 >> 8, hw = k4 & 255;
    f32x4 f = *(const f32x4*)&x[(((size_t)(b * CIN + c) * TT + t)) * 256 + hw];
    us4 o;
    #pragma unroll
    for (int i = 0; i < 4; ++i) o[i] = f2bf(f[i]);
    *(us4*)&xt[(size_t)n * DIN + k4] = o;
}

// ---------------------------------------------------------------------------
// MFMA GEMM, single M-tile: C[256][N] = A[256][K](bf16) * B[N][K]^T(fp32) + bias
// BM=256 BN=64 BK=64, 256 threads (4 waves), double-buffered LDS.
// B is fp32, converted to bf16 on the fly (read exactly once from HBM).
// ---------------------------------------------------------------------------
template<bool OUT_BF16>
__global__ __launch_bounds__(256, 2)
void mfma_gemm_kernel(const ushort_t* __restrict__ A, const float* __restrict__ B,
                      const float* __restrict__ bias, void* __restrict__ C,
                      int N, int K) {
    __shared__ ushort_t Al[2][256][64];   // 64 KB
    __shared__ ushort_t Bl[2][64][64];    // 16 KB
    int tid  = threadIdx.x;
    int lane = tid & 63;
    int wv   = tid >> 6;       // 0..3 : wave owns rows [wv*64, wv*64+64)
    int n0 = blockIdx.x * 64;

    f32x4 acc[4][4];
    #pragma unroll
    for (int i = 0; i < 4; ++i)
        #pragma unroll
        for (int j = 0; j < 4; ++j) acc[i][j] = (f32x4){0.f, 0.f, 0.f, 0.f};

    auto stageA = [&](int buf, int k0) {
        #pragma unroll
        for (int q = 0; q < 8; ++q) {
            int row = wv * 64 + q * 8 + (lane >> 3);
            const ushort_t* g = A + (size_t)row * K + k0 + (lane & 7) * 8;
            __builtin_amdgcn_global_load_lds(
                (const __attribute__((address_space(1))) void*)g,
                (__attribute__((address_space(3))) void*)&Al[buf][wv * 64 + q * 8][0],
                16, 0, 0);
        }
    };
    auto stageB = [&](int buf, int k0) {
        int r = tid >> 2;               // 0..63
        int cs = (tid & 3) * 16;        // 0,16,32,48
        const float* g = B + (size_t)(n0 + r) * K + k0 + cs;
        f32x4 f0 = *(const f32x4*)(g);
        f32x4 f1 = *(const f32x4*)(g + 4);
        f32x4 f2 = *(const f32x4*)(g + 8);
        f32x4 f3 = *(const f32x4*)(g + 12);
        union { ushort_t u[16]; bf16x8 v[2]; } pk;
        #pragma unroll
        for (int i = 0; i < 4; ++i) {
            pk.u[i]      = f2bf(f0[i]);
            pk.u[4 + i]  = f2bf(f1[i]);
            pk.u[8 + i]  = f2bf(f2[i]);
            pk.u[12 + i] = f2bf(f3[i]);
        }
        *(bf16x8*)&Bl[buf][r][cs]     = pk.v[0];
        *(bf16x8*)&Bl[buf][r][cs + 8] = pk.v[1];
    };
    auto compute = [&](int buf) {
        #pragma unroll
        for (int ks = 0; ks < 2; ++ks) {
            bf16x8 af[4], bfr[4];
            #pragma unroll
            for (int i = 0; i < 4; ++i)
                af[i] = *(const bf16x8*)&Al[buf][wv * 64 + i * 16 + (lane & 15)][ks * 32 + (lane >> 4) * 8];
            #pragma unroll
            for (int j = 0; j < 4; ++j)
                bfr[j] = *(const bf16x8*)&Bl[buf][j * 16 + (lane & 15)][ks * 32 + (lane >> 4) * 8];
            #pragma unroll
            for (int i = 0; i < 4; ++i)
                #pragma unroll
                for (int j = 0; j < 4; ++j)
                    acc[i][j] = __builtin_amdgcn_mfma_f32_16x16x32_bf16(af[i], bfr[j], acc[i][j], 0, 0, 0);
        }
    };

    stageA(0, 0); stageB(0, 0);
    __syncthreads();
    int nk = K / 64;
    int cur = 0;
    for (int t = 0; t < nk; ++t) {
        if (t + 1 < nk) { stageA(cur ^ 1, (t + 1) * 64); stageB(cur ^ 1, (t + 1) * 64); }
        compute(cur);
        __syncthreads();
        cur ^= 1;
    }

    #pragma unroll
    for (int i = 0; i < 4; ++i) {
        int row = wv * 64 + i * 16 + (lane >> 4) * 4;
        #pragma unroll
        for (int j = 0; j < 4; ++j) {
            int col = n0 + j * 16 + (lane & 15);
            float bv = bias[col];
            #pragma unroll
            for (int r = 0; r < 4; ++r) {
                float v = acc[i][j][r] + bv;
                if constexpr (OUT_BF16) ((ushort_t*)C)[(size_t)(row + r) * N + col] = f2bf(v);
                else                    ((float*)C)[(size_t)(row + r) * N + col] = v;
            }
        }
    }
}

// ---------------------------------------------------------------------------
// Cooperative full-sequence sLSTM: R staged once into LDS (fp32->bf16),
// 32 steps with grid.sync() between them.
// grid: 256 blocks = head(4) x ochunk(64 of 16 o's); 256 threads, wave = gate.
// h kept as hi+lo bf16 pair, PACKED into one MFMA (cols 0-7 hi, 8-15 lo),
// folded with shfl_xor(8). Ping-pong h buffers (8 x 4096 each).
// ---------------------------------------------------------------------------
__global__ __launch_bounds__(256, 1)
void lstm_seq_kernel(const float* __restrict__ R,       // [4][4][1024][1024] fp32
                     const float* __restrict__ Gx,      // [256][16384]
                     float* __restrict__ stc, float* __restrict__ stn,
                     float* __restrict__ stm,
                     ushort_t* __restrict__ hA_hi, ushort_t* __restrict__ hA_lo,
                     ushort_t* __restrict__ hB_hi, ushort_t* __restrict__ hB_lo,
                     float* __restrict__ hs) {
    __shared__ ushort_t Rl[4][32][16][32];   // [gate][ks][o_local][k] 128 KB
    __shared__ float gh_l[4][16][8];
    cg::grid_group grid = cg::this_grid();

    int tid  = threadIdx.x;
    int lane = tid & 63;
    int g    = tid >> 6;                 // gate = wave
    int head = blockIdx.x >> 6;
    int oc   = blockIdx.x & 63;

    // ---- stage R slice (4 gates x 16 o x 1024 k) fp32 -> bf16 LDS, once ----
    for (int idx = tid; idx < 8192; idx += 256) {
        int gg  = idx >> 11;
        int o_l = (idx >> 7) & 15;
        int ks  = (idx >> 2) & 31;
        int kI  = idx & 3;
        const float* src = R + ((size_t)((head * 4 + gg) * DH + oc * 16 + o_l)) * DH
                             + ks * 32 + kI * 8;
        f32x4 f0 = *(const f32x4*)src;
        f32x4 f1 = *(const f32x4*)(src + 4);
        union { ushort_t u[8]; bf16x8 v; } pk;
        #pragma unroll
        for (int j = 0; j < 4; ++j) { pk.u[j] = f2bf(f0[j]); pk.u[4 + j] = f2bf(f1[j]); }
        *(bf16x8*)&Rl[gg][ks][o_l][kI * 8] = pk.v;
    }
    __syncthreads();

    int arow = lane & 15;          // A row (o_local); also packed-B column
    int part = arow >> 3;          // 0: hi half of h, 1: lo half
    int bb   = arow & 7;           // batch
    int kseg = (lane >> 4) * 8;

    for (int t = 0; t < TT; ++t) {
        const ushort_t* hi_in = (t & 1) ? hB_hi : hA_hi;
        const ushort_t* lo_in = (t & 1) ? hB_lo : hA_lo;
        ushort_t* hi_out = (t & 1) ? hA_hi : hB_hi;
        ushort_t* lo_out = (t & 1) ? hA_lo : hB_lo;

        const ushort_t* Hp = (part ? lo_in : hi_in) + (size_t)bb * DOUT + head * DH + kseg;

        f32x4 accE = {0.f, 0.f, 0.f, 0.f};
        f32x4 accO = {0.f, 0.f, 0.f, 0.f};
        #pragma unroll 4
        for (int ks = 0; ks < 32; ks += 2) {
            bf16x8 r0 = *(const bf16x8*)&Rl[g][ks][arow][kseg];
            bf16x8 r1 = *(const bf16x8*)&Rl[g][ks + 1][arow][kseg];
            bf16x8 b0 = *(const bf16x8*)(Hp + ks * 32);
            bf16x8 b1 = *(const bf16x8*)(Hp + ks * 32 + 32);
            accE = __builtin_amdgcn_mfma_f32_16x16x32_bf16(r0, b0, accE, 0, 0, 0);
            accO = __builtin_amdgcn_mfma_f32_16x16x32_bf16(r1, b1, accO, 0, 0, 0);
        }
        f32x4 acc = accE + accO;
        // fold hi+lo: partner column = col ^ 8 -> partner lane = lane ^ 8
        #pragma unroll
        for (int r = 0; r < 4; ++r)
            acc[r] += __shfl_xor(acc[r], 8, 64);

        // D layout: col = lane&15 (= packed col), row = (lane>>4)*4 + r (= o_local)
        int orow0 = (lane >> 4) * 4;
        if (part == 0) {
            #pragma unroll
            for (int r = 0; r < 4; ++r) gh_l[g][orow0 + r][bb] = acc[r];
        }
        __syncthreads();

        if (tid < 128) {
            int b = tid >> 4, ol = tid & 15;
            int d = head * DH + oc * 16 + ol;
            int idx = b * DOUT + d;
            size_t gxoff = ((size_t)(b * TT + t)) * (4 * DOUT) + d;
            float ip = Gx[gxoff]            + gh_l[0][ol][b];
            float fp = Gx[gxoff + DOUT]     + gh_l[1][ol][b];
            float zp = Gx[gxoff + 2 * DOUT] + gh_l[2][ol][b];
            float op = Gx[gxoff + 3 * DOUT] + gh_l[3][ol][b];
            float mo = stm[idx];
            float mn = fmaxf(fp + mo, ip);
            float iv = expf(ip - mn);
            float fv = expf(fp + mo - mn);
            float cv = fv * stc[idx] + iv * tanhf(zp);
            float nv = fv * stn[idx] + iv;
            float sig = 1.f / (1.f + expf(-op));
            float hv = sig * cv / nv;
            stc[idx] = cv; stn[idx] = nv; stm[idx] = mn;
            hs[((size_t)(b * TT + t)) * DOUT + d] = hv;
            ushort_t hi = f2bf(hv);
            hi_out[idx] = hi;
            lo_out[idx] = f2bf(hv - bf2f(hi));
        }
        __threadfence();
        grid.sync();
    }
}

// ---------------------------------------------------------------------------
// conv3d 3x3x3 pad=1: one block per (b,t); LDS-staged input slice + weights.
// ---------------------------------------------------------------------------
__global__ __launch_bounds__(256)
void conv3d_kernel(const float* __restrict__ in, const float* __restrict__ w,
                   const float* __restrict__ bias, float* __restrict__ out, int relu) {
    __shared__ float xin[CIN][3][256];      // 48 KB
    __shared__ float wl[CIN][27][16];       // 27 KB, o-fastest
    int b = blockIdx.x >> 5, t = blockIdx.x & 31;
    int tid = threadIdx.x;

    for (int i = tid; i < CIN * 27 * 16; i += 256) {
        int o = i & 15, r = i >> 4;
        int k = r % 27, ci = r / 27;
        wl[ci][k][o] = w[(size_t)(o * CIN + ci) * 27 + k];
    }
    for (int i = tid; i < CIN * 3 * 256; i += 256) {
        int hw = i & 255, r = i >> 8;
        int kt = r % 3, ci = r / 3;
        int tt = t + kt - 1;
        xin[ci][kt][hw] = ((unsigned)tt < TT)
            ? in[((size_t)(b * CIN + ci) * TT + tt) * 256 + hw] : 0.f;
    }
    __syncthreads();

    int h = tid >> 4, wx = tid & 15;
    f32x4 a0 = *(const f32x4*)&bias[0];
    f32x4 a1 = *(const f32x4*)&bias[4];
    f32x4 a2 = *(const f32x4*)&bias[8];
    f32x4 a3 = *(const f32x4*)&bias[12];

    for (int ci = 0; ci < CIN; ++ci) {
        #pragma unroll
        for (int kt = 0; kt < 3; ++kt) {
            #pragma unroll
            for (int kh = 0; kh < 3; ++kh) {
                int h2 = h + kh - 1;
                if ((unsigned)h2 >= HH) continue;
                #pragma unroll
                for (int kw = 0; kw < 3; ++kw) {
                    int w2 = wx + kw - 1;
                    if ((unsigned)w2 >= WW) continue;
                    float xv = xin[ci][kt][h2 * 16 + w2];
                    int k = kt * 9 + kh * 3 + kw;
                    f32x4 w0 = *(const f32x4*)&wl[ci][k][0];
                    f32x4 w1 = *(const f32x4*)&wl[ci][k][4];
                    f32x4 w2v = *(const f32x4*)&wl[ci][k][8];
                    f32x4 w3 = *(const f32x4*)&wl[ci][k][12];
                    a0 += xv * w0; a1 += xv * w1; a2 += xv * w2v; a3 += xv * w3;
                }
            }
        }
    }
    float accs[16];
    #pragma unroll
    for (int i = 0; i < 4; ++i) { accs[i] = a0[i]; accs[4+i] = a1[i]; accs[8+i] = a2[i]; accs[12+i] = a3[i]; }
    #pragma unroll
    for (int o = 0; o < 16; ++o) {
        float v = accs[o];
        if (relu) v = fmaxf(v, 0.f);
        out[((size_t)(b * COUT + o) * TT + t) * 256 + tid] = v;
    }
}

// ---------------------------------------------------------------------------
// instance norm over (T,H,W) per (b,c) + relu, in place. 128 blocks.
// ---------------------------------------------------------------------------
__global__ void inorm_relu_kernel(float* __restrict__ y) {
    __shared__ float s1[256], s2[256];
    float* p = y + (size_t)blockIdx.x * SPAT;
    float sum = 0.f, sq = 0.f;
    for (int i = threadIdx.x; i < SPAT; i += 256) {
        float v = p[i];
        sum += v; sq += v * v;
    }
    s1[threadIdx.x] = sum; s2[threadIdx.x] = sq;
    __syncthreads();
    for (int s = 128; s > 0; s >>= 1) {
        if (threadIdx.x < s) { s1[threadIdx.x] += s1[threadIdx.x + s]; s2[threadIdx.x] += s2[threadIdx.x + s]; }
        __syncthreads();
    }
    float mu = s1[0] / (float)SPAT;
    float var = s2[0] / (float)SPAT - mu * mu;
    float rs = rsqrtf(var + 1e-5f);
    for (int i = threadIdx.x; i < SPAT; i += 256) {
        float v = (p[i] - mu) * rs;
        p[i] = fmaxf(v, 0.f);
    }
}

// ---------------------------------------------------------------------------
// final combine
// ---------------------------------------------------------------------------
__global__ void combine_kernel(const float* __restrict__ hs,
                               const float* __restrict__ out3d,
                               const float* __restrict__ attn_w,
                               const float* __restrict__ attn_b,
                               float* __restrict__ out) {
    int idx = blockIdx.x * 256 + threadIdx.x;
    int hw = idx & 255;
    int t  = (idx >> 8) & 31;
    int b  = idx >> 13;
    const float* hrow = hs + ((size_t)(b * TT + t)) * DOUT;
    float dot = attn_b[0];
    float sv[16], ov[16];
    #pragma unroll
    for (int ch = 0; ch < 16; ++ch) {
        float s  = hrow[ch * 256 + hw];
        float o3 = out3d[(((size_t)(b * COUT + ch) * TT + t)) * 256 + hw];
        sv[ch] = s; ov[ch] = o3;
        dot += attn_w[ch] * s + attn_w[16 + ch] * o3;
    }
    float alpha = 1.f / (1.f + expf(-dot));
    #pragma unroll
    for (int ch = 0; ch < 16; ++ch) {
        out[(((size_t)(b * COUT + ch) * TT + t)) * 256 + hw] =
            alpha * ov[ch] + (1.f - alpha) * sv[ch];
    }
}

// ---------------------------------------------------------------------------
extern "C" void kernel_launch(void* const* d_in, const int* in_sizes, int n_in,
                              void* d_out, int out_size, void* d_ws, size_t ws_size,
                              hipStream_t stream) {
    const float* x      = (const float*)d_in[0];
    const float* c1_w   = (const float*)d_in[1];
    const float* c1_b   = (const float*)d_in[2];
    const float* c2_w   = (const float*)d_in[3];
    const float* c2_b   = (const float*)d_in[4];
    const float* c3_w   = (const float*)d_in[5];
    const float* c3_b   = (const float*)d_in[6];
    const float* pre_w  = (const float*)d_in[7];
    const float* pre_b  = (const float*)d_in[8];
    const float* lstm_W = (const float*)d_in[9];
    const float* lstm_b = (const float*)d_in[10];
    const float* lstm_R = (const float*)d_in[11];
    const float* attn_w = (const float*)d_in[12];
    const float* attn_b = (const float*)d_in[13];
    float* out = (float*)d_out;

    // workspace carve (fp32 first, then bf16; all 16B aligned)
    float* wsf = (float*)d_ws;
    float* y1    = wsf;                // 1048576
    float* y2    = y1 + 1048576;       // 1048576
    float* out3d = y2 + 1048576;       // 1048576
    float* hs    = out3d + 1048576;    // 1048576
    float* Gx    = hs + 1048576;       // 4194304
    float* stc   = Gx + 4194304;       // 32768
    float* stn   = stc + 32768;        // 32768
    float* stm   = stn + 32768;        // 32768
    ushort_t* xt    = (ushort_t*)(stm + 32768);   // 1048576
    ushort_t* xs2b  = xt + 1048576;               // 1048576
    ushort_t* hA_hi = xs2b + 1048576;             // 32768 (8 x 4096)
    ushort_t* hA_lo = hA_hi + 32768;              // 32768
    ushort_t* hB_hi = hA_lo + 32768;              // 32768
    ushort_t* hB_lo = hB_hi + 32768;              // 32768

    // zero c,n,m (contiguous fp32) and the t=0 input h buffers (hi+lo)
    hipMemsetAsync(stc, 0, 3 * 32768 * sizeof(float), stream);
    hipMemsetAsync(hA_hi, 0, 2 * 32768 * sizeof(ushort_t), stream);

    // pack x -> bf16 sequence layout
    pack_xt_kernel<<<1024, 256, 0, stream>>>(x, xt);

    // convs
    conv3d_kernel<<<256, 256, 0, stream>>>(x, c1_w, c1_b, y1, 0);
    inorm_relu_kernel<<<128, 256, 0, stream>>>(y1);
    conv3d_kernel<<<256, 256, 0, stream>>>(y1, c2_w, c2_b, y2, 1);
    conv3d_kernel<<<256, 256, 0, stream>>>(y2, c3_w, c3_b, out3d, 1);

    // pre-projection -> xs2 (bf16); gate projection -> Gx (fp32)
    mfma_gemm_kernel<true><<<DOUT / 64, 256, 0, stream>>>(xt, pre_w, pre_b, xs2b, DOUT, DIN);
    mfma_gemm_kernel<false><<<4 * DOUT / 64, 256, 0, stream>>>(xs2b, lstm_W, lstm_b, Gx, 4 * DOUT, DOUT);

    // recurrence: one cooperative kernel, 32 steps with grid sync
    void* cargs[] = {(void*)&lstm_R, (void*)&Gx, (void*)&stc, (void*)&stn, (void*)&stm,
                     (void*)&hA_hi, (void*)&hA_lo, (void*)&hB_hi, (void*)&hB_lo, (void*)&hs};
    hipLaunchCooperativeKernel((void*)lstm_seq_kernel, dim3(256), dim3(256), cargs, 0, stream);

    // combine
    combine_kernel<<<256, 256, 0, stream>>>(hs, out3d, attn_w, attn_b, out);
}

// Round 5
// 754.011 us; speedup vs baseline: 3.2832x; 3.2832x over previous
//
#include <hip/hip_runtime.h>
#include <hip/hip_bf16.h>
#include <cstddef>

// Problem constants
#define BB   8
#define CIN  16
#define COUT 16
#define TT   32
#define HH   16
#define WW   16
#define DIN  4096
#define DOUT 4096
#define NH   4
#define DH   1024
#define SPAT 8192            // T*H*W
#define NSEQ 256             // B*T

typedef __attribute__((ext_vector_type(8))) short  bf16x8;
typedef __attribute__((ext_vector_type(4))) float  f32x4;
typedef __attribute__((ext_vector_type(4))) unsigned short us4;
typedef unsigned short ushort_t;

static __device__ __forceinline__ ushort_t f2bf(float f) {
    union { float f; unsigned u; } v; v.f = f;
    unsigned r = (v.u + 0x7fffu + ((v.u >> 16) & 1u)) >> 16;
    return (ushort_t)r;
}
static __device__ __forceinline__ float bf2f(ushort_t u) {
    union { unsigned u; float f; } v; v.u = ((unsigned)u) << 16;
    return v.f;
}

// ---------------------------------------------------------------------------
// pack x (B,16,32,16,16) fp32 -> xt[n=b*32+t][k=c*256+hw] bf16
// ---------------------------------------------------------------------------
__global__ void pack_xt_kernel(const float* __restrict__ x, ushort_t* __restrict__ xt) {
    int idx = blockIdx.x * 256 + threadIdx.x;          // 0 .. 262143 (4 elems each)
    int n = idx >> 10, k4 = (idx & 1023) * 4;
    int b = n >> 5, t = n & 31, c = k4 >> 8, hw = k4 & 255;
    f32x4 f = *(const f32x4*)&x[(((size_t)(b * CIN + c) * TT + t)) * 256 + hw];
    us4 o;
    #pragma unroll
    for (int i = 0; i < 4; ++i) o[i] = f2bf(f[i]);
    *(us4*)&xt[(size_t)n * DIN + k4] = o;
}

// ---------------------------------------------------------------------------
// pack R (4,4,1024,1024) fp32 -> bf16 in MFMA-fragment order:
// Rp[((head*64+oc)*4+g)*32+ks][lane][e] = R[head][g][oc*16+(lane&15)][ks*32+(lane>>4)*8+e]
// One thread per 8-elem fragment vector.  Per-step reads become lane-contiguous.
// ---------------------------------------------------------------------------
__global__ void pack_R_kernel(const float* __restrict__ R, ushort_t* __restrict__ Rp) {
    int vid = blockIdx.x * 256 + threadIdx.x;   // 0 .. 2097151
    int l  = vid & 63;
    int ks = (vid >> 6) & 31;
    int g  = (vid >> 11) & 3;
    int oc = (vid >> 13) & 63;
    int hd = vid >> 19;
    int arow = l & 15, kI = l >> 4;
    const float* src = R + ((size_t)((hd * 4 + g) * DH + oc * 16 + arow)) * DH
                         + ks * 32 + kI * 8;
    f32x4 f0 = *(const f32x4*)src;
    f32x4 f1 = *(const f32x4*)(src + 4);
    union { ushort_t u[8]; bf16x8 v; } pk;
    #pragma unroll
    for (int j = 0; j < 4; ++j) { pk.u[j] = f2bf(f0[j]); pk.u[4 + j] = f2bf(f1[j]); }
    ((bf16x8*)Rp)[vid] = pk.v;
}

// ---------------------------------------------------------------------------
// MFMA GEMM, single M-tile: C[256][N] = A[256][K](bf16) * B[N][K]^T(fp32) + bias
// BM=256 BN=64 BK=64, 256 threads (4 waves), double-buffered LDS.
// ---------------------------------------------------------------------------
template<bool OUT_BF16>
__global__ __launch_bounds__(256, 2)
void mfma_gemm_kernel(const ushort_t* __restrict__ A, const float* __restrict__ B,
                      const float* __restrict__ bias, void* __restrict__ C,
                      int N, int K) {
    __shared__ ushort_t Al[2][256][64];   // 64 KB
    __shared__ ushort_t Bl[2][64][64];    // 16 KB
    int tid  = threadIdx.x;
    int lane = tid & 63;
    int wv   = tid >> 6;       // 0..3 : wave owns rows [wv*64, wv*64+64)
    int n0 = blockIdx.x * 64;

    f32x4 acc[4][4];
    #pragma unroll
    for (int i = 0; i < 4; ++i)
        #pragma unroll
        for (int j = 0; j < 4; ++j) acc[i][j] = (f32x4){0.f, 0.f, 0.f, 0.f};

    auto stageA = [&](int buf, int k0) {
        #pragma unroll
        for (int q = 0; q < 8; ++q) {
            int row = wv * 64 + q * 8 + (lane >> 3);
            const ushort_t* g = A + (size_t)row * K + k0 + (lane & 7) * 8;
            __builtin_amdgcn_global_load_lds(
                (const __attribute__((address_space(1))) void*)g,
                (__attribute__((address_space(3))) void*)&Al[buf][wv * 64 + q * 8][0],
                16, 0, 0);
        }
    };
    auto stageB = [&](int buf, int k0) {
        int r = tid >> 2;               // 0..63
        int cs = (tid & 3) * 16;        // 0,16,32,48
        const float* g = B + (size_t)(n0 + r) * K + k0 + cs;
        f32x4 f0 = *(const f32x4*)(g);
        f32x4 f1 = *(const f32x4*)(g + 4);
        f32x4 f2 = *(const f32x4*)(g + 8);
        f32x4 f3 = *(const f32x4*)(g + 12);
        union { ushort_t u[16]; bf16x8 v[2]; } pk;
        #pragma unroll
        for (int i = 0; i < 4; ++i) {
            pk.u[i]      = f2bf(f0[i]);
            pk.u[4 + i]  = f2bf(f1[i]);
            pk.u[8 + i]  = f2bf(f2[i]);
            pk.u[12 + i] = f2bf(f3[i]);
        }
        *(bf16x8*)&Bl[buf][r][cs]     = pk.v[0];
        *(bf16x8*)&Bl[buf][r][cs + 8] = pk.v[1];
    };
    auto compute = [&](int buf) {
        #pragma unroll
        for (int ks = 0; ks < 2; ++ks) {
            bf16x8 af[4], bfr[4];
            #pragma unroll
            for (int i = 0; i < 4; ++i)
                af[i] = *(const bf16x8*)&Al[buf][wv * 64 + i * 16 + (lane & 15)][ks * 32 + (lane >> 4) * 8];
            #pragma unroll
            for (int j = 0; j < 4; ++j)
                bfr[j] = *(const bf16x8*)&Bl[buf][j * 16 + (lane & 15)][ks * 32 + (lane >> 4) * 8];
            #pragma unroll
            for (int i = 0; i < 4; ++i)
                #pragma unroll
                for (int j = 0; j < 4; ++j)
                    acc[i][j] = __builtin_amdgcn_mfma_f32_16x16x32_bf16(af[i], bfr[j], acc[i][j], 0, 0, 0);
        }
    };

    stageA(0, 0); stageB(0, 0);
    __syncthreads();
    int nk = K / 64;
    int cur = 0;
    for (int t = 0; t < nk; ++t) {
        if (t + 1 < nk) { stageA(cur ^ 1, (t + 1) * 64); stageB(cur ^ 1, (t + 1) * 64); }
        compute(cur);
        __syncthreads();
        cur ^= 1;
    }

    #pragma unroll
    for (int i = 0; i < 4; ++i) {
        int row = wv * 64 + i * 16 + (lane >> 4) * 4;
        #pragma unroll
        for (int j = 0; j < 4; ++j) {
            int col = n0 + j * 16 + (lane & 15);
            float bv = bias[col];
            #pragma unroll
            for (int r = 0; r < 4; ++r) {
                float v = acc[i][j][r] + bv;
                if constexpr (OUT_BF16) ((ushort_t*)C)[(size_t)(row + r) * N + col] = f2bf(v);
                else                    ((float*)C)[(size_t)(row + r) * N + col] = v;
            }
        }
    }
}

// ---------------------------------------------------------------------------
// Fused sLSTM step: gh (block-diagonal MFMA with packed-coalesced R) + gates.
// grid: 256 blocks = head(4) x ochunk(64 of 16 o's); 256 threads, wave = gate.
// h kept as hi+lo bf16 pair PACKED into one MFMA (cols 0-7 hi, 8-15 lo),
// folded with shfl_xor(8).  Ping-pong h buffers; launch boundary = barrier.
// ---------------------------------------------------------------------------
__global__ __launch_bounds__(256)
void lstm_step_kernel(const ushort_t* __restrict__ Rp,     // packed bf16 (32 MB)
                      const ushort_t* __restrict__ h_hi,   // [8][4096]
                      const ushort_t* __restrict__ h_lo,
                      const float* __restrict__ Gx,        // [256][16384]
                      float* __restrict__ stc, float* __restrict__ stn,
                      float* __restrict__ stm,
                      ushort_t* __restrict__ ho_hi, ushort_t* __restrict__ ho_lo,
                      float* __restrict__ hs, int t) {
    __shared__ float gh_l[4][16][8];
    int tid  = threadIdx.x;
    int lane = tid & 63;
    int g    = tid >> 6;                 // gate = wave
    int head = blockIdx.x >> 6;
    int oc   = blockIdx.x & 63;

    int arow = lane & 15;          // A row (o_local); also packed-B column
    int part = arow >> 3;          // 0: hi half of h, 1: lo half
    int bb   = arow & 7;           // batch
    int kseg = (lane >> 4) * 8;

    const bf16x8* Rw = (const bf16x8*)Rp
        + ((size_t)((head * 64 + oc) * 4 + g) * 32) * 64 + lane;   // Rw[ks*64]
    const ushort_t* Hp = (part ? h_lo : h_hi) + (size_t)bb * DOUT + head * DH + kseg;

    f32x4 accE = {0.f, 0.f, 0.f, 0.f};
    f32x4 accO = {0.f, 0.f, 0.f, 0.f};
    #pragma unroll 4
    for (int ks = 0; ks < 32; ks += 2) {
        bf16x8 r0 = Rw[ks * 64];
        bf16x8 r1 = Rw[(ks + 1) * 64];
        bf16x8 b0 = *(const bf16x8*)(Hp + ks * 32);
        bf16x8 b1 = *(const bf16x8*)(Hp + ks * 32 + 32);
        accE = __builtin_amdgcn_mfma_f32_16x16x32_bf16(r0, b0, accE, 0, 0, 0);
        accO = __builtin_amdgcn_mfma_f32_16x16x32_bf16(r1, b1, accO, 0, 0, 0);
    }
    f32x4 acc = accE + accO;
    // fold hi+lo halves: partner column = col ^ 8 -> partner lane = lane ^ 8
    #pragma unroll
    for (int r = 0; r < 4; ++r)
        acc[r] += __shfl_xor(acc[r], 8, 64);

    // D layout: col = lane&15, row = (lane>>4)*4 + r (= o_local)
    int orow0 = (lane >> 4) * 4;
    if (part == 0) {
        #pragma unroll
        for (int r = 0; r < 4; ++r) gh_l[g][orow0 + r][bb] = acc[r];
    }
    __syncthreads();

    if (tid < 128) {
        int b = tid >> 4, ol = tid & 15;
        int d = head * DH + oc * 16 + ol;
        int idx = b * DOUT + d;
        size_t gxoff = ((size_t)(b * TT + t)) * (4 * DOUT) + d;
        float ip = Gx[gxoff]            + gh_l[0][ol][b];
        float fp = Gx[gxoff + DOUT]     + gh_l[1][ol][b];
        float zp = Gx[gxoff + 2 * DOUT] + gh_l[2][ol][b];
        float op = Gx[gxoff + 3 * DOUT] + gh_l[3][ol][b];
        float mo = stm[idx];
        float mn = fmaxf(fp + mo, ip);
        float iv = expf(ip - mn);
        float fv = expf(fp + mo - mn);
        float cv = fv * stc[idx] + iv * tanhf(zp);
        float nv = fv * stn[idx] + iv;
        float sig = 1.f / (1.f + expf(-op));
        float hv = sig * cv / nv;
        stc[idx] = cv; stn[idx] = nv; stm[idx] = mn;
        hs[((size_t)(b * TT + t)) * DOUT + d] = hv;
        ushort_t hi = f2bf(hv);
        ho_hi[idx] = hi;
        ho_lo[idx] = f2bf(hv - bf2f(hi));
    }
}

// ---------------------------------------------------------------------------
// conv3d 3x3x3 pad=1: one block per (b,t); LDS-staged input slice + weights.
// ---------------------------------------------------------------------------
__global__ __launch_bounds__(256)
void conv3d_kernel(const float* __restrict__ in, const float* __restrict__ w,
                   const float* __restrict__ bias, float* __restrict__ out, int relu) {
    __shared__ float xin[CIN][3][256];      // 48 KB
    __shared__ float wl[CIN][27][16];       // 27 KB, o-fastest
    int b = blockIdx.x >> 5, t = blockIdx.x & 31;
    int tid = threadIdx.x;

    for (int i = tid; i < CIN * 27 * 16; i += 256) {
        int o = i & 15, r = i >> 4;
        int k = r % 27, ci = r / 27;
        wl[ci][k][o] = w[(size_t)(o * CIN + ci) * 27 + k];
    }
    for (int i = tid; i < CIN * 3 * 256; i += 256) {
        int hw = i & 255, r = i >> 8;
        int kt = r % 3, ci = r / 3;
        int tt = t + kt - 1;
        xin[ci][kt][hw] = ((unsigned)tt < TT)
            ? in[((size_t)(b * CIN + ci) * TT + tt) * 256 + hw] : 0.f;
    }
    __syncthreads();

    int h = tid >> 4, wx = tid & 15;
    f32x4 a0 = *(const f32x4*)&bias[0];
    f32x4 a1 = *(const f32x4*)&bias[4];
    f32x4 a2 = *(const f32x4*)&bias[8];
    f32x4 a3 = *(const f32x4*)&bias[12];

    for (int ci = 0; ci < CIN; ++ci) {
        #pragma unroll
        for (int kt = 0; kt < 3; ++kt) {
            #pragma unroll
            for (int kh = 0; kh < 3; ++kh) {
                int h2 = h + kh - 1;
                if ((unsigned)h2 >= HH) continue;
                #pragma unroll
                for (int kw = 0; kw < 3; ++kw) {
                    int w2 = wx + kw - 1;
                    if ((unsigned)w2 >= WW) continue;
                    float xv = xin[ci][kt][h2 * 16 + w2];
                    int k = kt * 9 + kh * 3 + kw;
                    f32x4 w0 = *(const f32x4*)&wl[ci][k][0];
                    f32x4 w1 = *(const f32x4*)&wl[ci][k][4];
                    f32x4 w2v = *(const f32x4*)&wl[ci][k][8];
                    f32x4 w3 = *(const f32x4*)&wl[ci][k][12];
                    a0 += xv * w0; a1 += xv * w1; a2 += xv * w2v; a3 += xv * w3;
                }
            }
        }
    }
    float accs[16];
    #pragma unroll
    for (int i = 0; i < 4; ++i) { accs[i] = a0[i]; accs[4+i] = a1[i]; accs[8+i] = a2[i]; accs[12+i] = a3[i]; }
    #pragma unroll
    for (int o = 0; o < 16; ++o) {
        float v = accs[o];
        if (relu) v = fmaxf(v, 0.f);
        out[((size_t)(b * COUT + o) * TT + t) * 256 + tid] = v;
    }
}

// ---------------------------------------------------------------------------
// instance norm over (T,H,W) per (b,c) + relu, in place. 128 blocks.
// ---------------------------------------------------------------------------
__global__ void inorm_relu_kernel(float* __restrict__ y) {
    __shared__ float s1[256], s2[256];
    float* p = y + (size_t)blockIdx.x * SPAT;
    float sum = 0.f, sq = 0.f;
    for (int i = threadIdx.x; i < SPAT; i += 256) {
        float v = p[i];
        sum += v; sq += v * v;
    }
    s1[threadIdx.x] = sum; s2[threadIdx.x] = sq;
    __syncthreads();
    for (int s = 128; s > 0; s >>= 1) {
        if (threadIdx.x < s) { s1[threadIdx.x] += s1[threadIdx.x + s]; s2[threadIdx.x] += s2[threadIdx.x + s]; }
        __syncthreads();
    }
    float mu = s1[0] / (float)SPAT;
    float var = s2[0] / (float)SPAT - mu * mu;
    float rs = rsqrtf(var + 1e-5f);
    for (int i = threadIdx.x; i < SPAT; i += 256) {
        float v = (p[i] - mu) * rs;
        p[i] = fmaxf(v, 0.f);
    }
}

// ---------------------------------------------------------------------------
// final combine
// ---------------------------------------------------------------------------
__global__ void combine_kernel(const float* __restrict__ hs,
                               const float* __restrict__ out3d,
                               const float* __restrict__ attn_w,
                               const float* __restrict__ attn_b,
                               float* __restrict__ out) {
    int idx = blockIdx.x * 256 + threadIdx.x;
    int hw = idx & 255;
    int t  = (idx >> 8) & 31;
    int b  = idx >> 13;
    const float* hrow = hs + ((size_t)(b * TT + t)) * DOUT;
    float dot = attn_b[0];
    float sv[16], ov[16];
    #pragma unroll
    for (int ch = 0; ch < 16; ++ch) {
        float s  = hrow[ch * 256 + hw];
        float o3 = out3d[(((size_t)(b * COUT + ch) * TT + t)) * 256 + hw];
        sv[ch] = s; ov[ch] = o3;
        dot += attn_w[ch] * s + attn_w[16 + ch] * o3;
    }
    float alpha = 1.f / (1.f + expf(-dot));
    #pragma unroll
    for (int ch = 0; ch < 16; ++ch) {
        out[(((size_t)(b * COUT + ch) * TT + t)) * 256 + hw] =
            alpha * ov[ch] + (1.f - alpha) * sv[ch];
    }
}

// ---------------------------------------------------------------------------
extern "C" void kernel_launch(void* const* d_in, const int* in_sizes, int n_in,
                              void* d_out, int out_size, void* d_ws, size_t ws_size,
                              hipStream_t stream) {
    const float* x      = (const float*)d_in[0];
    const float* c1_w   = (const float*)d_in[1];
    const float* c1_b   = (const float*)d_in[2];
    const float* c2_w   = (const float*)d_in[3];
    const float* c2_b   = (const float*)d_in[4];
    const float* c3_w   = (const float*)d_in[5];
    const float* c3_b   = (const float*)d_in[6];
    const float* pre_w  = (const float*)d_in[7];
    const float* pre_b  = (const float*)d_in[8];
    const float* lstm_W = (const float*)d_in[9];
    const float* lstm_b = (const float*)d_in[10];
    const float* lstm_R = (const float*)d_in[11];
    const float* attn_w = (const float*)d_in[12];
    const float* attn_b = (const float*)d_in[13];
    float* out = (float*)d_out;

    // workspace carve (fp32 first, then bf16; all 16B aligned)
    float* wsf = (float*)d_ws;
    float* y1    = wsf;                // 1048576
    float* y2    = y1 + 1048576;       // 1048576
    float* out3d = y2 + 1048576;       // 1048576
    float* hs    = out3d + 1048576;    // 1048576
    float* Gx    = hs + 1048576;       // 4194304
    float* stc   = Gx + 4194304;       // 32768
    float* stn   = stc + 32768;        // 32768
    float* stm   = stn + 32768;        // 32768
    ushort_t* xt    = (ushort_t*)(stm + 32768);   // 1048576
    ushort_t* xs2b  = xt + 1048576;               // 1048576
    ushort_t* Rp    = xs2b + 1048576;             // 16777216 (packed R, 32 MB)
    ushort_t* hA_hi = Rp + 16777216;              // 32768 (8 x 4096)
    ushort_t* hA_lo = hA_hi + 32768;              // 32768
    ushort_t* hB_hi = hA_lo + 32768;              // 32768
    ushort_t* hB_lo = hB_hi + 32768;              // 32768

    // zero c,n,m (contiguous fp32) and the t=0 input h buffers (hi+lo)
    hipMemsetAsync(stc, 0, 3 * 32768 * sizeof(float), stream);
    hipMemsetAsync(hA_hi, 0, 2 * 32768 * sizeof(ushort_t), stream);

    // pack x -> bf16 sequence layout; pack R -> bf16 MFMA-fragment order
    pack_xt_kernel<<<1024, 256, 0, stream>>>(x, xt);
    pack_R_kernel<<<8192, 256, 0, stream>>>(lstm_R, Rp);

    // convs
    conv3d_kernel<<<256, 256, 0, stream>>>(x, c1_w, c1_b, y1, 0);
    inorm_relu_kernel<<<128, 256, 0, stream>>>(y1);
    conv3d_kernel<<<256, 256, 0, stream>>>(y1, c2_w, c2_b, y2, 1);
    conv3d_kernel<<<256, 256, 0, stream>>>(y2, c3_w, c3_b, out3d, 1);

    // pre-projection -> xs2 (bf16); gate projection -> Gx (fp32)
    mfma_gemm_kernel<true><<<DOUT / 64, 256, 0, stream>>>(xt, pre_w, pre_b, xs2b, DOUT, DIN);
    mfma_gemm_kernel<false><<<4 * DOUT / 64, 256, 0, stream>>>(xs2b, lstm_W, lstm_b, Gx, 4 * DOUT, DOUT);

    // recurrence: 32 per-step launches (launch boundary = device-wide barrier)
    for (int t = 0; t < TT; ++t) {
        const ushort_t* hi_in = (t & 1) ? hB_hi : hA_hi;
        const ushort_t* lo_in = (t & 1) ? hB_lo : hA_lo;
        ushort_t* hi_out = (t & 1) ? hA_hi : hB_hi;
        ushort_t* lo_out = (t & 1) ? hA_lo : hB_lo;
        lstm_step_kernel<<<256, 256, 0, stream>>>(Rp, hi_in, lo_in, Gx,
                                                  stc, stn, stm, hi_out, lo_out, hs, t);
    }

    // combine
    combine_kernel<<<256, 256, 0, stream>>>(hs, out3d, attn_w, attn_b, out);
}